// Round 5
// baseline (60.423 us; speedup 1.0000x reference)
//
#include <hip/hip_runtime.h>
#include <math.h>

#define NPARAMS 104                         // N_LAYERS * N_QUBITS
#define DIM 8192
#define NELEM ((size_t)DIM * (size_t)DIM)   // 67108864 floats, 268.4 MB
#define RB 2048                             // reduce blocks
#define RT 256                              // threads/block
#define NTHREADS ((size_t)RB * RT)          // 524288
#define N4 (NELEM / 4)                      // 16777216 float4
#define ITERS (int)(N4 / NTHREADS)          // exactly 32

typedef __attribute__((ext_vector_type(4))) float f32x4;

// ---------------------------------------------------------------------------
// Kernel 1: R4's proven globally-strided float4 partial reduce, with ONE
// change: nontemporal (streaming) loads, so the zero-reuse 268 MB stream
// doesn't pay L2 allocate/evict churn. 8 loads in flight, 4 independent
// fp32 accumulators, ~56 VGPR -> full 32 waves/CU. Replay-safe (no atomics).
// ---------------------------------------------------------------------------
__global__ __launch_bounds__(RT) void vqe_reduce(
    const float* __restrict__ H, float* __restrict__ partials) {
    const f32x4* __restrict__ H4 = reinterpret_cast<const f32x4*>(H);
    const size_t tid = (size_t)blockIdx.x * RT + threadIdx.x;

    float a0 = 0.f, a1 = 0.f, a2 = 0.f, a3 = 0.f;
    #pragma unroll 1
    for (int i = 0; i < ITERS; i += 8) {
        f32x4 v0 = __builtin_nontemporal_load(H4 + tid + (size_t)(i + 0) * NTHREADS);
        f32x4 v1 = __builtin_nontemporal_load(H4 + tid + (size_t)(i + 1) * NTHREADS);
        f32x4 v2 = __builtin_nontemporal_load(H4 + tid + (size_t)(i + 2) * NTHREADS);
        f32x4 v3 = __builtin_nontemporal_load(H4 + tid + (size_t)(i + 3) * NTHREADS);
        f32x4 v4 = __builtin_nontemporal_load(H4 + tid + (size_t)(i + 4) * NTHREADS);
        f32x4 v5 = __builtin_nontemporal_load(H4 + tid + (size_t)(i + 5) * NTHREADS);
        f32x4 v6 = __builtin_nontemporal_load(H4 + tid + (size_t)(i + 6) * NTHREADS);
        f32x4 v7 = __builtin_nontemporal_load(H4 + tid + (size_t)(i + 7) * NTHREADS);
        a0 += (v0[0] + v0[1]) + (v0[2] + v0[3]);
        a1 += (v1[0] + v1[1]) + (v1[2] + v1[3]);
        a2 += (v2[0] + v2[1]) + (v2[2] + v2[3]);
        a3 += (v3[0] + v3[1]) + (v3[2] + v3[3]);
        a0 += (v4[0] + v4[1]) + (v4[2] + v4[3]);
        a1 += (v5[0] + v5[1]) + (v5[2] + v5[3]);
        a2 += (v6[0] + v6[1]) + (v6[2] + v6[3]);
        a3 += (v7[0] + v7[1]) + (v7[2] + v7[3]);
    }
    float acc = (a0 + a1) + (a2 + a3);

    // wave-64 shuffle reduction
    #pragma unroll
    for (int off = 32; off > 0; off >>= 1)
        acc += __shfl_down(acc, off, 64);

    __shared__ float wsum[RT / 64];
    const int lane = threadIdx.x & 63;
    const int wid  = threadIdx.x >> 6;
    if (lane == 0) wsum[wid] = acc;
    __syncthreads();

    if (threadIdx.x == 0)
        partials[blockIdx.x] = (wsum[0] + wsum[1]) + (wsum[2] + wsum[3]);
}

// ---------------------------------------------------------------------------
// Kernel 2: fp64 sum of 2048 float partials; analytic global phase
// e^{i*sum(theta)/2}; write energy + uniform state (interleaved re/im).
// ---------------------------------------------------------------------------
__global__ __launch_bounds__(RT) void vqe_finalize(
    const float* __restrict__ partials,
    const float* __restrict__ params, float* __restrict__ out) {

    double s = 0.0;
    #pragma unroll
    for (int i = threadIdx.x; i < RB; i += RT) s += (double)partials[i];

    #pragma unroll
    for (int off = 32; off > 0; off >>= 1)
        s += __shfl_down(s, off, 64);

    __shared__ double wsum[RT / 64];
    __shared__ double total_sh;
    const int lane = threadIdx.x & 63;
    const int wid  = threadIdx.x >> 6;
    if (lane == 0) wsum[wid] = s;
    __syncthreads();
    if (threadIdx.x == 0)
        total_sh = (wsum[0] + wsum[1]) + (wsum[2] + wsum[3]);
    __syncthreads();

    // renormalized product of unit phasors == phasor of the summed angles
    float ang = 0.f;
    for (int k = 0; k < NPARAMS; ++k) ang += params[k];
    ang *= 0.5f;
    const float pr = cosf(ang);
    const float pq = sinf(ang);
    const float invsq = 1.0f / sqrtf((float)DIM);
    const float sr = pr * invsq;
    const float si = pq * invsq;

    for (int j = threadIdx.x; j < DIM; j += RT) {
        out[1 + 2 * j] = sr;
        out[2 + 2 * j] = si;
    }
    if (threadIdx.x == 0) {
        const double norm2 = (double)sr * sr + (double)si * si;  // ~1/8192
        out[0] = (float)(total_sh * norm2);
    }
}

extern "C" void kernel_launch(void* const* d_in, const int* in_sizes, int n_in,
                              void* d_out, int out_size, void* d_ws, size_t ws_size,
                              hipStream_t stream) {
    const float* params = (const float*)d_in[0];   // 104 floats
    const float* H      = (const float*)d_in[1];   // 8192*8192 floats
    float* out          = (float*)d_out;           // [energy, re0, im0, ...]
    float* partials     = (float*)d_ws;            // RB floats of scratch

    vqe_reduce<<<RB, RT, 0, stream>>>(H, partials);
    vqe_finalize<<<1, RT, 0, stream>>>(partials, params, out);
    (void)in_sizes; (void)n_in; (void)out_size; (void)ws_size;
}

// Round 6
// 59.760 us; speedup vs baseline: 1.0111x; 1.0111x over previous
//
#include <hip/hip_runtime.h>
#include <math.h>

#define NPARAMS 104                         // N_LAYERS * N_QUBITS
#define DIM 8192
#define NELEM ((size_t)DIM * (size_t)DIM)   // 67108864 floats, 268.4 MB
#define RB 1024                             // blocks: 4096 waves << capacity -> one scheduling round
#define RT 256                              // threads/block
#define NTHREADS ((size_t)RB * RT)          // 262144
#define N4 (NELEM / 4)                      // 16777216 float4
#define ITERS (int)(N4 / NTHREADS)          // exactly 64

typedef __attribute__((ext_vector_type(4))) float f32x4;

// ---------------------------------------------------------------------------
// Kernel 1: globally-strided float4 partial reduce. ONE change vs R4: grid
// halved to 1024 blocks so the launch is single-round-schedulable regardless
// of the compiler's exact VGPR count (2048 blocks = 8192 waves needed VGPR<=64
// to fit in one round; a 65-VGPR build runs a ~256-block tail at low
// parallelism). 8 loads in flight, 4 independent fp32 accumulators.
// ---------------------------------------------------------------------------
__global__ __launch_bounds__(RT) void vqe_reduce(
    const float* __restrict__ H, float* __restrict__ partials) {
    const f32x4* __restrict__ H4 = reinterpret_cast<const f32x4*>(H);
    const size_t tid = (size_t)blockIdx.x * RT + threadIdx.x;

    float a0 = 0.f, a1 = 0.f, a2 = 0.f, a3 = 0.f;
    #pragma unroll 1
    for (int i = 0; i < ITERS; i += 8) {
        f32x4 v0 = H4[tid + (size_t)(i + 0) * NTHREADS];
        f32x4 v1 = H4[tid + (size_t)(i + 1) * NTHREADS];
        f32x4 v2 = H4[tid + (size_t)(i + 2) * NTHREADS];
        f32x4 v3 = H4[tid + (size_t)(i + 3) * NTHREADS];
        f32x4 v4 = H4[tid + (size_t)(i + 4) * NTHREADS];
        f32x4 v5 = H4[tid + (size_t)(i + 5) * NTHREADS];
        f32x4 v6 = H4[tid + (size_t)(i + 6) * NTHREADS];
        f32x4 v7 = H4[tid + (size_t)(i + 7) * NTHREADS];
        a0 += (v0[0] + v0[1]) + (v0[2] + v0[3]);
        a1 += (v1[0] + v1[1]) + (v1[2] + v1[3]);
        a2 += (v2[0] + v2[1]) + (v2[2] + v2[3]);
        a3 += (v3[0] + v3[1]) + (v3[2] + v3[3]);
        a0 += (v4[0] + v4[1]) + (v4[2] + v4[3]);
        a1 += (v5[0] + v5[1]) + (v5[2] + v5[3]);
        a2 += (v6[0] + v6[1]) + (v6[2] + v6[3]);
        a3 += (v7[0] + v7[1]) + (v7[2] + v7[3]);
    }
    float acc = (a0 + a1) + (a2 + a3);

    // wave-64 shuffle reduction
    #pragma unroll
    for (int off = 32; off > 0; off >>= 1)
        acc += __shfl_down(acc, off, 64);

    __shared__ float wsum[RT / 64];
    const int lane = threadIdx.x & 63;
    const int wid  = threadIdx.x >> 6;
    if (lane == 0) wsum[wid] = acc;
    __syncthreads();

    if (threadIdx.x == 0)
        partials[blockIdx.x] = (wsum[0] + wsum[1]) + (wsum[2] + wsum[3]);
}

// ---------------------------------------------------------------------------
// Kernel 2: fp64 sum of 1024 float partials; analytic global phase
// e^{i*sum(theta)/2}; write energy + uniform state (interleaved re/im).
// ---------------------------------------------------------------------------
__global__ __launch_bounds__(RT) void vqe_finalize(
    const float* __restrict__ partials,
    const float* __restrict__ params, float* __restrict__ out) {

    double s = 0.0;
    #pragma unroll
    for (int i = threadIdx.x; i < RB; i += RT) s += (double)partials[i];

    #pragma unroll
    for (int off = 32; off > 0; off >>= 1)
        s += __shfl_down(s, off, 64);

    __shared__ double wsum[RT / 64];
    __shared__ double total_sh;
    const int lane = threadIdx.x & 63;
    const int wid  = threadIdx.x >> 6;
    if (lane == 0) wsum[wid] = s;
    __syncthreads();
    if (threadIdx.x == 0)
        total_sh = (wsum[0] + wsum[1]) + (wsum[2] + wsum[3]);
    __syncthreads();

    // renormalized product of unit phasors == phasor of the summed angles
    float ang = 0.f;
    for (int k = 0; k < NPARAMS; ++k) ang += params[k];
    ang *= 0.5f;
    const float pr = cosf(ang);
    const float pq = sinf(ang);
    const float invsq = 1.0f / sqrtf((float)DIM);
    const float sr = pr * invsq;
    const float si = pq * invsq;

    for (int j = threadIdx.x; j < DIM; j += RT) {
        out[1 + 2 * j] = sr;
        out[2 + 2 * j] = si;
    }
    if (threadIdx.x == 0) {
        const double norm2 = (double)sr * sr + (double)si * si;  // ~1/8192
        out[0] = (float)(total_sh * norm2);
    }
}

extern "C" void kernel_launch(void* const* d_in, const int* in_sizes, int n_in,
                              void* d_out, int out_size, void* d_ws, size_t ws_size,
                              hipStream_t stream) {
    const float* params = (const float*)d_in[0];   // 104 floats
    const float* H      = (const float*)d_in[1];   // 8192*8192 floats
    float* out          = (float*)d_out;           // [energy, re0, im0, ...]
    float* partials     = (float*)d_ws;            // RB floats of scratch

    vqe_reduce<<<RB, RT, 0, stream>>>(H, partials);
    vqe_finalize<<<1, RT, 0, stream>>>(partials, params, out);
    (void)in_sizes; (void)n_in; (void)out_size; (void)ws_size;
}

// Round 7
// 59.556 us; speedup vs baseline: 1.0146x; 1.0034x over previous
//
#include <hip/hip_runtime.h>
#include <math.h>

#define NPARAMS 104                         // N_LAYERS * N_QUBITS
#define DIM 8192
#define NELEM ((size_t)DIM * (size_t)DIM)   // 67108864 floats, 268.4 MB
#define RB 1024                             // blocks (single-round schedulable)
#define RT 256                              // threads/block
#define NTHREADS ((size_t)RB * RT)          // 262144
#define N4 (NELEM / 4)                      // 16777216 float4
#define ITERS (int)(N4 / NTHREADS)          // exactly 64

typedef __attribute__((ext_vector_type(4))) float f32x4;

// ---------------------------------------------------------------------------
// Kernel 1: split-stream reduce. ONE change vs R6: within each 8-load body,
// loads 0-3 are PLAIN (their 4MB super-chunks -> L3-resident across graph
// replays: fixed 134 MB set, fits 256 MB Infinity Cache) and loads 4-7 are
// NONTEMPORAL (stream past L3 from HBM). L3 and HBM paths serve concurrent
// halves of the sweep instead of thrashing one path. Same addresses, same
// accumulator mapping -> bitwise-identical result to R4/R5/R6.
// ---------------------------------------------------------------------------
__global__ __launch_bounds__(RT) void vqe_reduce(
    const float* __restrict__ H, float* __restrict__ partials) {
    const f32x4* __restrict__ H4 = reinterpret_cast<const f32x4*>(H);
    const size_t tid = (size_t)blockIdx.x * RT + threadIdx.x;

    float a0 = 0.f, a1 = 0.f, a2 = 0.f, a3 = 0.f;
    #pragma unroll 1
    for (int i = 0; i < ITERS; i += 8) {
        f32x4 v0 = H4[tid + (size_t)(i + 0) * NTHREADS];                           // L3-resident half
        f32x4 v1 = H4[tid + (size_t)(i + 1) * NTHREADS];
        f32x4 v2 = H4[tid + (size_t)(i + 2) * NTHREADS];
        f32x4 v3 = H4[tid + (size_t)(i + 3) * NTHREADS];
        f32x4 v4 = __builtin_nontemporal_load(H4 + tid + (size_t)(i + 4) * NTHREADS); // HBM-stream half
        f32x4 v5 = __builtin_nontemporal_load(H4 + tid + (size_t)(i + 5) * NTHREADS);
        f32x4 v6 = __builtin_nontemporal_load(H4 + tid + (size_t)(i + 6) * NTHREADS);
        f32x4 v7 = __builtin_nontemporal_load(H4 + tid + (size_t)(i + 7) * NTHREADS);
        a0 += (v0[0] + v0[1]) + (v0[2] + v0[3]);
        a1 += (v1[0] + v1[1]) + (v1[2] + v1[3]);
        a2 += (v2[0] + v2[1]) + (v2[2] + v2[3]);
        a3 += (v3[0] + v3[1]) + (v3[2] + v3[3]);
        a0 += (v4[0] + v4[1]) + (v4[2] + v4[3]);
        a1 += (v5[0] + v5[1]) + (v5[2] + v5[3]);
        a2 += (v6[0] + v6[1]) + (v6[2] + v6[3]);
        a3 += (v7[0] + v7[1]) + (v7[2] + v7[3]);
    }
    float acc = (a0 + a1) + (a2 + a3);

    // wave-64 shuffle reduction
    #pragma unroll
    for (int off = 32; off > 0; off >>= 1)
        acc += __shfl_down(acc, off, 64);

    __shared__ float wsum[RT / 64];
    const int lane = threadIdx.x & 63;
    const int wid  = threadIdx.x >> 6;
    if (lane == 0) wsum[wid] = acc;
    __syncthreads();

    if (threadIdx.x == 0)
        partials[blockIdx.x] = (wsum[0] + wsum[1]) + (wsum[2] + wsum[3]);
}

// ---------------------------------------------------------------------------
// Kernel 2: fp64 sum of 1024 float partials; analytic global phase
// e^{i*sum(theta)/2}; write energy + uniform state (interleaved re/im).
// ---------------------------------------------------------------------------
__global__ __launch_bounds__(RT) void vqe_finalize(
    const float* __restrict__ partials,
    const float* __restrict__ params, float* __restrict__ out) {

    double s = 0.0;
    #pragma unroll
    for (int i = threadIdx.x; i < RB; i += RT) s += (double)partials[i];

    #pragma unroll
    for (int off = 32; off > 0; off >>= 1)
        s += __shfl_down(s, off, 64);

    __shared__ double wsum[RT / 64];
    __shared__ double total_sh;
    const int lane = threadIdx.x & 63;
    const int wid  = threadIdx.x >> 6;
    if (lane == 0) wsum[wid] = s;
    __syncthreads();
    if (threadIdx.x == 0)
        total_sh = (wsum[0] + wsum[1]) + (wsum[2] + wsum[3]);
    __syncthreads();

    // renormalized product of unit phasors == phasor of the summed angles
    float ang = 0.f;
    for (int k = 0; k < NPARAMS; ++k) ang += params[k];
    ang *= 0.5f;
    const float pr = cosf(ang);
    const float pq = sinf(ang);
    const float invsq = 1.0f / sqrtf((float)DIM);
    const float sr = pr * invsq;
    const float si = pq * invsq;

    for (int j = threadIdx.x; j < DIM; j += RT) {
        out[1 + 2 * j] = sr;
        out[2 + 2 * j] = si;
    }
    if (threadIdx.x == 0) {
        const double norm2 = (double)sr * sr + (double)si * si;  // ~1/8192
        out[0] = (float)(total_sh * norm2);
    }
}

extern "C" void kernel_launch(void* const* d_in, const int* in_sizes, int n_in,
                              void* d_out, int out_size, void* d_ws, size_t ws_size,
                              hipStream_t stream) {
    const float* params = (const float*)d_in[0];   // 104 floats
    const float* H      = (const float*)d_in[1];   // 8192*8192 floats
    float* out          = (float*)d_out;           // [energy, re0, im0, ...]
    float* partials     = (float*)d_ws;            // RB floats of scratch

    vqe_reduce<<<RB, RT, 0, stream>>>(H, partials);
    vqe_finalize<<<1, RT, 0, stream>>>(partials, params, out);
    (void)in_sizes; (void)n_in; (void)out_size; (void)ws_size;
}

// Round 8
// 55.908 us; speedup vs baseline: 1.0808x; 1.0652x over previous
//
#include <hip/hip_runtime.h>
#include <math.h>

#define NPARAMS 104                         // N_LAYERS * N_QUBITS
#define DIM 8192
#define NELEM ((size_t)DIM * (size_t)DIM)   // 67108864 floats, 268.4 MB
#define RB 1024                             // blocks
#define RT 256                              // threads/block
#define NTHREADS ((size_t)RB * RT)          // 262144
#define N4 (NELEM / 4)                      // 16777216 float4
#define ITERS (int)(N4 / NTHREADS)          // exactly 64
#define SPB (DIM / RB)                      // 8 state entries per block

typedef __attribute__((ext_vector_type(4))) float f32x4;

// ---------------------------------------------------------------------------
// Kernel 1: R6's proven streaming reduce (plain loads, 8 in flight, pinned at
// the ~5 TB/s pure-read ceiling) + NEW epilogue: each block also writes its
// 8-entry slice of the uniform state (64 B), with the phase angle computed by
// a parallel reduce over params. Moves the 64 KB state write off the finalize
// kernel's critical path (0.02% added traffic here, fully parallel).
// ---------------------------------------------------------------------------
__global__ __launch_bounds__(RT) void vqe_reduce_state(
    const float* __restrict__ H, const float* __restrict__ params,
    float* __restrict__ out, float* __restrict__ partials) {
    const f32x4* __restrict__ H4 = reinterpret_cast<const f32x4*>(H);
    const size_t tid = (size_t)blockIdx.x * RT + threadIdx.x;

    float a0 = 0.f, a1 = 0.f, a2 = 0.f, a3 = 0.f;
    #pragma unroll 1
    for (int i = 0; i < ITERS; i += 8) {
        f32x4 v0 = H4[tid + (size_t)(i + 0) * NTHREADS];
        f32x4 v1 = H4[tid + (size_t)(i + 1) * NTHREADS];
        f32x4 v2 = H4[tid + (size_t)(i + 2) * NTHREADS];
        f32x4 v3 = H4[tid + (size_t)(i + 3) * NTHREADS];
        f32x4 v4 = H4[tid + (size_t)(i + 4) * NTHREADS];
        f32x4 v5 = H4[tid + (size_t)(i + 5) * NTHREADS];
        f32x4 v6 = H4[tid + (size_t)(i + 6) * NTHREADS];
        f32x4 v7 = H4[tid + (size_t)(i + 7) * NTHREADS];
        a0 += (v0[0] + v0[1]) + (v0[2] + v0[3]);
        a1 += (v1[0] + v1[1]) + (v1[2] + v1[3]);
        a2 += (v2[0] + v2[1]) + (v2[2] + v2[3]);
        a3 += (v3[0] + v3[1]) + (v3[2] + v3[3]);
        a0 += (v4[0] + v4[1]) + (v4[2] + v4[3]);
        a1 += (v5[0] + v5[1]) + (v5[2] + v5[3]);
        a2 += (v6[0] + v6[1]) + (v6[2] + v6[3]);
        a3 += (v7[0] + v7[1]) + (v7[2] + v7[3]);
    }
    float acc = (a0 + a1) + (a2 + a3);

    // wave-64 shuffle reduction of the block partial
    #pragma unroll
    for (int off = 32; off > 0; off >>= 1)
        acc += __shfl_down(acc, off, 64);

    __shared__ float wsum[RT / 64];
    __shared__ float sr_sh, si_sh;
    const int lane = threadIdx.x & 63;
    const int wid  = threadIdx.x >> 6;
    if (lane == 0) wsum[wid] = acc;
    __syncthreads();
    if (threadIdx.x == 0)
        partials[blockIdx.x] = (wsum[0] + wsum[1]) + (wsum[2] + wsum[3]);

    // --- state epilogue: ang = sum(params) via parallel reduce (~300 ns) ---
    float pv = (threadIdx.x < NPARAMS) ? params[threadIdx.x] : 0.f;
    #pragma unroll
    for (int off = 32; off > 0; off >>= 1)
        pv += __shfl_down(pv, off, 64);

    __shared__ float asum[RT / 64];
    if (lane == 0) asum[wid] = pv;
    __syncthreads();
    if (threadIdx.x == 0) {
        // renormalized product of unit phasors == phasor of summed angles
        const float ang = ((asum[0] + asum[1]) + (asum[2] + asum[3])) * 0.5f;
        const float invsq = 1.0f / sqrtf((float)DIM);
        sr_sh = cosf(ang) * invsq;
        si_sh = sinf(ang) * invsq;
    }
    __syncthreads();
    if (threadIdx.x < SPB) {
        const int j = blockIdx.x * SPB + threadIdx.x;
        out[1 + 2 * j] = sr_sh;
        out[2 + 2 * j] = si_sh;
    }
}

// ---------------------------------------------------------------------------
// Kernel 2 (slim): one block sums 1024 float partials (float4 loads, fp64
// accumulate) and writes out[0] = energy. No state write anymore.
// ---------------------------------------------------------------------------
__global__ __launch_bounds__(RT) void vqe_finalize(
    const float* __restrict__ partials,
    const float* __restrict__ params, float* __restrict__ out) {

    const f32x4* __restrict__ p4 = reinterpret_cast<const f32x4*>(partials);
    const f32x4 v = p4[threadIdx.x];            // 256 threads x 4 = 1024
    double s = ((double)v[0] + (double)v[1]) + ((double)v[2] + (double)v[3]);

    #pragma unroll
    for (int off = 32; off > 0; off >>= 1)
        s += __shfl_down(s, off, 64);

    __shared__ double wsum[RT / 64];
    const int lane = threadIdx.x & 63;
    const int wid  = threadIdx.x >> 6;
    if (lane == 0) wsum[wid] = s;
    __syncthreads();

    if (threadIdx.x == 0) {
        const double total = (wsum[0] + wsum[1]) + (wsum[2] + wsum[3]);
        float ang = 0.f;
        for (int k = 0; k < NPARAMS; ++k) ang += params[k];
        ang *= 0.5f;
        const float invsq = 1.0f / sqrtf((float)DIM);
        const float sr = cosf(ang) * invsq;
        const float si = sinf(ang) * invsq;
        const double norm2 = (double)sr * sr + (double)si * si;  // ~1/8192
        out[0] = (float)(total * norm2);
    }
}

extern "C" void kernel_launch(void* const* d_in, const int* in_sizes, int n_in,
                              void* d_out, int out_size, void* d_ws, size_t ws_size,
                              hipStream_t stream) {
    const float* params = (const float*)d_in[0];   // 104 floats
    const float* H      = (const float*)d_in[1];   // 8192*8192 floats
    float* out          = (float*)d_out;           // [energy, re0, im0, ...]
    float* partials     = (float*)d_ws;            // RB floats of scratch

    vqe_reduce_state<<<RB, RT, 0, stream>>>(H, params, out, partials);
    vqe_finalize<<<1, RT, 0, stream>>>(partials, params, out);
    (void)in_sizes; (void)n_in; (void)out_size; (void)ws_size;
}